// Round 1
// baseline (42.499 us; speedup 1.0000x reference)
//
#include <hip/hip_runtime.h>

#define N_ROWS 8192
#define DIM 128
#define BM 128
#define CHUNK 1024
#define BN 64
#define NITER (CHUNK/BN)      // 16
#define NCHUNK (N_ROWS/CHUNK) // 8

typedef __attribute__((ext_vector_type(8))) short short8;
typedef __attribute__((ext_vector_type(4))) float f32x4;

__device__ __forceinline__ void gload_lds16(const void* g, void* l) {
  __builtin_amdgcn_global_load_lds(
      (const __attribute__((address_space(1))) void*)g,
      (__attribute__((address_space(3))) void*)l, 16, 0, 0);
}

__device__ __forceinline__ unsigned short f2bf(float x) {
  unsigned int u = __float_as_uint(x);
  unsigned int r = (u + 0x7fffu + ((u >> 16) & 1u)) >> 16;
  return (unsigned short)r;
}

// Kernel 1: L2-normalize rows, write bf16 pre-swizzled (16B chunk ^ (row&7)).
__global__ __launch_bounds__(256) void knorm(const float* __restrict__ feat,
                                             unsigned int* __restrict__ fn) {
  const int wid = threadIdx.x >> 6;
  const int lane = threadIdx.x & 63;
  const int row = blockIdx.x * 4 + wid;
  const float2 v = *(const float2*)(feat + (size_t)row * DIM + lane * 2);
  float s = v.x * v.x + v.y * v.y;
#pragma unroll
  for (int m = 1; m < 64; m <<= 1) s += __shfl_xor(s, m);
  const float inv = 1.0f / fmaxf(sqrtf(s), 1e-12f);
  const unsigned int pk = (unsigned int)f2bf(v.x * inv) |
                          ((unsigned int)f2bf(v.y * inv) << 16);
  const int chunk = (lane >> 2) ^ (row & 7);
  fn[row * 64 + chunk * 4 + (lane & 3)] = pk;
}

// Kernel 2: fused bf16 MFMA sim + exp + masked row sums (per column-chunk partials).
__global__ __launch_bounds__(256, 2) void ksim(const unsigned int* __restrict__ fn,
                                               const float* __restrict__ alphap,
                                               float* __restrict__ posP,
                                               float* __restrict__ totP) {
  __shared__ __align__(16) char smem[65536];  // A: [0,32K) ; B dbuf: [32K,64K)
  const int tid = threadIdx.x;
  const int lane = tid & 63;
  const int wid = tid >> 6;
  const int wr = wid >> 1, wc = wid & 1;
  const int r0 = blockIdx.x * BM;
  const int c0 = blockIdx.y * CHUNK;
  const float alpha = alphap[0];
  const float K2 = 14.285714285714286f;  // 1/TAU

  const char* fbytes = (const char*)fn;

  // Stage A panel (128 rows x 256 B) — linear copy of pre-swizzled global.
  {
    const char* g = fbytes + (size_t)(r0 + wid * 32 + (lane >> 4)) * 256 + (lane & 15) * 16;
    char* l = smem + wid * 8192;
#pragma unroll
    for (int s = 0; s < 8; s++) gload_lds16(g + s * 1024, l + s * 1024);
  }
  // Stage B tile 0.
  {
    const char* g = fbytes + (size_t)(c0 + wid * 16 + (lane >> 4)) * 256 + (lane & 15) * 16;
    char* l = smem + 32768 + wid * 4096;
#pragma unroll
    for (int s = 0; s < 4; s++) gload_lds16(g + s * 1024, l + s * 1024);
  }
  __syncthreads();

  // Hoist A fragments to registers: 4 m-frags x 4 k-steps x 16B.
  short8 aR[4][4];
  {
    const int lrb = wr * 64 + (lane & 15);
#pragma unroll
    for (int m = 0; m < 4; m++) {
      const int r = lrb + m * 16;
#pragma unroll
      for (int ks = 0; ks < 4; ks++) {
        const int ch = (ks * 4 + (lane >> 4)) ^ (r & 7);
        aR[m][ks] = *(const short8*)(smem + r * 256 + ch * 16);
      }
    }
  }

  float pp[4][4] = {{0.f}}, tp[4][4] = {{0.f}};
  int cur = 0;

  for (int it = 0; it < NITER; ++it) {
    if (it + 1 < NITER) {  // stage next B tile into other buffer
      const int cb = c0 + (it + 1) * BN;
      const char* g = fbytes + (size_t)(cb + wid * 16 + (lane >> 4)) * 256 + (lane & 15) * 16;
      char* l = smem + 32768 + (cur ^ 1) * 16384 + wid * 4096;
#pragma unroll
      for (int s = 0; s < 4; s++) gload_lds16(g + s * 1024, l + s * 1024);
    }

    f32x4 acc[4][2];
#pragma unroll
    for (int m = 0; m < 4; m++)
#pragma unroll
      for (int n = 0; n < 2; n++) acc[m][n] = (f32x4){0.f, 0.f, 0.f, 0.f};

    const char* Bbase = smem + 32768 + cur * 16384;
    const int colA = wc * 32 + (lane & 15);
#pragma unroll
    for (int ks = 0; ks < 4; ks++) {
      const int ch = (ks * 4 + (lane >> 4)) ^ (colA & 7);
      short8 b0 = *(const short8*)(Bbase + colA * 256 + ch * 16);
      short8 b1 = *(const short8*)(Bbase + (colA + 16) * 256 + ch * 16);
#pragma unroll
      for (int m = 0; m < 4; m++) {
        acc[m][0] = __builtin_amdgcn_mfma_f32_16x16x32_bf16(aR[m][ks], b0, acc[m][0], 0, 0, 0);
        acc[m][1] = __builtin_amdgcn_mfma_f32_16x16x32_bf16(aR[m][ks], b1, acc[m][1], 0, 0, 0);
      }
    }

    // Epilogue: e = exp(sim/tau); tot += e (j!=i); pos += e if sim>=alpha.
    const int cb = c0 + it * BN;
#pragma unroll
    for (int m = 0; m < 4; m++) {
      const int grb = r0 + wr * 64 + m * 16;  // 16-aligned fragment row base
#pragma unroll
      for (int n = 0; n < 2; n++) {
        const int gcb = cb + wc * 32 + n * 16;  // 16-aligned fragment col base
        const f32x4 a = acc[m][n];
        if (grb == gcb) {  // diagonal fragment: per-element exclusion
          const int gr0 = (lane >> 4) << 2;
          const int gcl = lane & 15;
#pragma unroll
          for (int r = 0; r < 4; r++) {
            const float e = __expf(a[r] * K2);
            const float ev = (gr0 + r == gcl) ? 0.0f : e;
            tp[m][r] += ev;
            pp[m][r] += (a[r] >= alpha) ? ev : 0.0f;
          }
        } else {
#pragma unroll
          for (int r = 0; r < 4; r++) {
            const float e = __expf(a[r] * K2);
            tp[m][r] += e;
            pp[m][r] += (a[r] >= alpha) ? e : 0.0f;
          }
        }
      }
    }
    __syncthreads();
    cur ^= 1;
  }

  // Intra-wave reduce over the 16 column-lanes of each row group.
#pragma unroll
  for (int m = 0; m < 4; m++)
#pragma unroll
    for (int r = 0; r < 4; r++) {
      float p = pp[m][r], t = tp[m][r];
#pragma unroll
      for (int msk = 1; msk < 16; msk <<= 1) {
        p += __shfl_xor(p, msk);
        t += __shfl_xor(t, msk);
      }
      pp[m][r] = p;
      tp[m][r] = t;
    }

  float* red = (float*)smem;  // [4 waves][64 rows][2], reuses dead A region
  if ((lane & 15) == 0) {
    const int g = lane >> 4;
#pragma unroll
    for (int m = 0; m < 4; m++)
#pragma unroll
      for (int r = 0; r < 4; r++) {
        const int rl = m * 16 + g * 4 + r;
        red[(wid * 64 + rl) * 2 + 0] = pp[m][r];
        red[(wid * 64 + rl) * 2 + 1] = tp[m][r];
      }
  }
  __syncthreads();
  if (tid < BM) {
    const int wrr = tid >> 6, rl = tid & 63;
    const float p = red[((wrr * 2 + 0) * 64 + rl) * 2 + 0] + red[((wrr * 2 + 1) * 64 + rl) * 2 + 0];
    const float t = red[((wrr * 2 + 0) * 64 + rl) * 2 + 1] + red[((wrr * 2 + 1) * 64 + rl) * 2 + 1];
    posP[blockIdx.y * N_ROWS + r0 + tid] = p;
    totP[blockIdx.y * N_ROWS + r0 + tid] = t;
  }
}

// Kernel 3a: per-row loss term, 128-row blocks -> 64 partial sums.
__global__ __launch_bounds__(128) void kred1(const float* __restrict__ posP,
                                             const float* __restrict__ totP,
                                             float* __restrict__ bp) {
  const int t = threadIdx.x;
  const int row = blockIdx.x * 128 + t;
  float pos = 0.f, tot = 0.f;
#pragma unroll
  for (int c = 0; c < NCHUNK; c++) {
    pos += posP[c * N_ROWS + row];
    tot += totP[c * N_ROWS + row];
  }
  float term = __logf(tot + 2e-10f) - __logf(pos + 1e-10f);
#pragma unroll
  for (int m = 1; m < 64; m <<= 1) term += __shfl_xor(term, m);
  __shared__ float s2[2];
  if ((t & 63) == 0) s2[t >> 6] = term;
  __syncthreads();
  if (t == 0) bp[blockIdx.x] = s2[0] + s2[1];
}

// Kernel 3b: final mean.
__global__ void kred2(const float* __restrict__ bp, float* __restrict__ out) {
  const int l = threadIdx.x;
  float v = bp[l];
#pragma unroll
  for (int m = 1; m < 64; m <<= 1) v += __shfl_xor(v, m);
  if (l == 0) out[0] = v * (1.0f / 8192.0f);
}

extern "C" void kernel_launch(void* const* d_in, const int* in_sizes, int n_in,
                              void* d_out, int out_size, void* d_ws, size_t ws_size,
                              hipStream_t stream) {
  const float* feat = (const float*)d_in[0];
  const float* alphap = (const float*)d_in[1];
  char* ws = (char*)d_ws;
  unsigned int* fn = (unsigned int*)ws;                       // 2 MB bf16 swizzled
  float* posP = (float*)(ws + (2u << 20));                    // 256 KB
  float* totP = (float*)(ws + (2u << 20) + (256u << 10));     // 256 KB
  float* bp = (float*)(ws + (2u << 20) + (512u << 10));       // 256 B
  float* out = (float*)d_out;

  knorm<<<dim3(N_ROWS / 4), dim3(256), 0, stream>>>(feat, fn);
  ksim<<<dim3(N_ROWS / BM, NCHUNK), dim3(256), 0, stream>>>(fn, alphap, posP, totP);
  kred1<<<dim3(N_ROWS / 128), dim3(128), 0, stream>>>(posP, totP, bp);
  kred2<<<dim3(1), dim3(64), 0, stream>>>(bp, out);
}